// Round 1
// baseline (470.836 us; speedup 1.0000x reference)
//
#include <hip/hip_runtime.h>
#include <hip/hip_bf16.h>
#include <stdint.h>

typedef uint32_t u32;
typedef unsigned short u16;

#define NLAT_I 361
#define NLON_I 720
#define NLAT_O 181
#define NLON_O 360
#define KK 9
#define NNZ 120000
#define NSEG (KK * NLAT_O)            /* 1629 */
#define NPIX (NLAT_O * NLON_O)        /* 65160 */
#define NCH 32
#define NCP 16                        /* channel pairs */
#define XP_TOTAL (NLAT_I * 2 * NLON_O * NCP)  /* 4,158,720 u32 */

__device__ __forceinline__ u32 f2bf_rne(float f) {
    u32 b = __float_as_uint(f);
    return (b + 0x7FFFu + ((b >> 16) & 1u)) >> 16;
}

// ---------------- repack: x[32][361][720] f32 -> xp[hi][p][j][cp] bf16x2 ----
__global__ __launch_bounds__(256) void repack_kernel(const float* __restrict__ x,
                                                     u32* __restrict__ xp) {
    int tid = blockIdx.x * 256 + threadIdx.x;
    if (tid >= XP_TOTAL) return;
    int cp = tid & (NCP - 1);
    int j  = (tid >> 4) % NLON_O;
    int r  = tid / (NCP * NLON_O);    // r = hi*2 + p
    int p  = r & 1;
    int hi = r >> 1;
    int col = 2 * j + p;
    const int plane = NLAT_I * NLON_I;
    float f0 = x[(2 * cp) * plane + hi * NLON_I + col];
    float f1 = x[(2 * cp + 1) * plane + hi * NLON_I + col];
    xp[tid] = f2bf_rne(f0) | (f2bf_rne(f1) << 16);
}

// ---------------- CSR build ------------------------------------------------
__global__ __launch_bounds__(256) void hist_kernel(const int* __restrict__ ker,
                                                   const int* __restrict__ row,
                                                   int* __restrict__ counts) {
    int e = blockIdx.x * 256 + threadIdx.x;
    if (e >= NNZ) return;
    int seg = ker[e] * NLAT_O + row[e];
    atomicAdd(&counts[seg], 1);
}

__global__ __launch_bounds__(256) void scan_kernel(const int* __restrict__ counts,
                                                   int* __restrict__ offsets) {
    __shared__ int lsum[256];
    const int CH = 7;                  // 256*7 = 1792 >= 1629
    int t = threadIdx.x;
    int base = t * CH;
    int local[CH];
    int s = 0;
    for (int i = 0; i < CH; i++) {
        int v = (base + i < NSEG) ? counts[base + i] : 0;
        local[i] = s;
        s += v;
    }
    lsum[t] = s;
    __syncthreads();
    for (int off = 1; off < 256; off <<= 1) {
        int v = 0;
        if (t >= off) v = lsum[t - off];
        __syncthreads();
        if (t >= off) lsum[t] += v;
        __syncthreads();
    }
    int pre = (t == 0) ? 0 : lsum[t - 1];
    for (int i = 0; i < CH; i++) {
        if (base + i < NSEG) offsets[base + i] = pre + local[i];
    }
}

__global__ __launch_bounds__(256) void scatter_kernel(const int* __restrict__ ker,
                                                      const int* __restrict__ row,
                                                      const int* __restrict__ col,
                                                      const float* __restrict__ vals,
                                                      const int* __restrict__ offsets,
                                                      int* __restrict__ cursor,
                                                      u32* __restrict__ meta,
                                                      float* __restrict__ mval) {
    int e = blockIdx.x * 256 + threadIdx.x;
    if (e >= NNZ) return;
    int seg = ker[e] * NLAT_O + row[e];
    int pos = offsets[seg] + atomicAdd(&cursor[seg], 1);
    int c  = col[e];
    int hi = c / NLON_I;
    int wi = c % NLON_I;
    int p  = wi & 1;
    int a  = wi >> 1;                  // < 360
    meta[pos] = ((u32)hi << 10) | ((u32)p << 9) | (u32)a;
    mval[pos] = vals[e];
}

// ---------------- stage1: per-segment gather-accumulate --------------------
#define UNP(u, c0)                                          \
    {                                                       \
        float lo_ = __uint_as_float((u) << 16);             \
        float hi_ = __uint_as_float((u) & 0xFFFF0000u);     \
        acc[c0] = fmaf(v, lo_, acc[c0]);                    \
        acc[c0 + 1] = fmaf(v, hi_, acc[c0 + 1]);            \
    }

__global__ __launch_bounds__(384) void stage1_kernel(const u32* __restrict__ xp,
                                                     const int* __restrict__ offs,
                                                     const int* __restrict__ cnts,
                                                     const u32* __restrict__ meta,
                                                     const float* __restrict__ mval,
                                                     u16* __restrict__ xk) {
    int s = blockIdx.x;
    int k = s / NLAT_O;
    int ho = s % NLAT_O;
    int wo = threadIdx.x;
    bool act = wo < NLON_O;
    int w = act ? wo : 0;

    float acc[NCH];
#pragma unroll
    for (int c = 0; c < NCH; c++) acc[c] = 0.0f;

    int start = offs[s];
    int cnt = cnts[s];
    for (int i = 0; i < cnt; i++) {
        u32 m = meta[start + i];
        float v = mval[start + i];
        int hi = m >> 10;
        int p = (m >> 9) & 1;
        int a = m & 0x1FF;
        int idx = a + w;
        idx = (idx >= NLON_O) ? idx - NLON_O : idx;
        const uint4* rp =
            (const uint4*)(xp + ((size_t)(((hi << 1) + p) * NLON_O + idx) << 4));
        uint4 q0 = rp[0];
        uint4 q1 = rp[1];
        uint4 q2 = rp[2];
        uint4 q3 = rp[3];
        UNP(q0.x, 0)  UNP(q0.y, 2)  UNP(q0.z, 4)  UNP(q0.w, 6)
        UNP(q1.x, 8)  UNP(q1.y, 10) UNP(q1.z, 12) UNP(q1.w, 14)
        UNP(q2.x, 16) UNP(q2.y, 18) UNP(q2.z, 20) UNP(q2.w, 22)
        UNP(q3.x, 24) UNP(q3.y, 26) UNP(q3.z, 28) UNP(q3.w, 30)
    }

    if (act) {
        int pix = ho * NLON_O + wo;
#pragma unroll
        for (int c = 0; c < NCH; c++) {
            xk[(size_t)(c * KK + k) * NPIX + pix] = (u16)f2bf_rne(acc[c]);
        }
    }
}

// ---------------- stage2: out[32][65160] = W[32][288] * xk[288][65160] -----
__global__ __launch_bounds__(256) void stage2_kernel(const u16* __restrict__ xk,
                                                     const float* __restrict__ W,
                                                     const float* __restrict__ bias,
                                                     float* __restrict__ out) {
    int pix = blockIdx.x * 256 + threadIdx.x;
    bool act = pix < NPIX;
    int px = act ? pix : 0;
    float acc[NCH];
#pragma unroll
    for (int o = 0; o < NCH; o++) acc[o] = 0.0f;
    for (int r = 0; r < NCH * KK; r++) {
        float xv = __uint_as_float(((u32)xk[(size_t)r * NPIX + px]) << 16);
#pragma unroll
        for (int o = 0; o < NCH; o++) {
            acc[o] = fmaf(W[o * (NCH * KK) + r], xv, acc[o]);
        }
    }
    if (act) {
#pragma unroll
        for (int o = 0; o < NCH; o++) {
            out[(size_t)o * NPIX + pix] = acc[o] + bias[o];
        }
    }
}

// ---------------- launch ---------------------------------------------------
extern "C" void kernel_launch(void* const* d_in, const int* in_sizes, int n_in,
                              void* d_out, int out_size, void* d_ws, size_t ws_size,
                              hipStream_t stream) {
    const float* x    = (const float*)d_in[0];
    const int* ker    = (const int*)d_in[1];
    const int* row    = (const int*)d_in[2];
    const int* col    = (const int*)d_in[3];
    const float* vals = (const float*)d_in[4];
    const float* W    = (const float*)d_in[5];
    const float* bias = (const float*)d_in[6];
    float* out        = (float*)d_out;

    char* ws = (char*)d_ws;
    const size_t off_xp   = 0;
    const size_t sz_xp    = (size_t)XP_TOTAL * 4;              // 16,634,880
    const size_t off_cnt  = off_xp + sz_xp;
    const size_t off_off  = off_cnt + 6528;
    const size_t off_cur  = off_off + 6528;
    const size_t off_meta = off_cur + 6528;
    const size_t off_val  = off_meta + (size_t)NNZ * 4;
    const size_t off_xk   = off_val + (size_t)NNZ * 4;

    u32* xp      = (u32*)(ws + off_xp);
    int* counts  = (int*)(ws + off_cnt);
    int* offsets = (int*)(ws + off_off);
    int* cursor  = (int*)(ws + off_cur);
    u32* meta    = (u32*)(ws + off_meta);
    float* mval  = (float*)(ws + off_val);
    u16* xk      = (u16*)(ws + off_xk);

    // zero counts + offsets + cursor
    hipMemsetAsync(ws + off_cnt, 0, 3 * 6528, stream);

    repack_kernel<<<(XP_TOTAL + 255) / 256, 256, 0, stream>>>(x, xp);
    hist_kernel<<<(NNZ + 255) / 256, 256, 0, stream>>>(ker, row, counts);
    scan_kernel<<<1, 256, 0, stream>>>(counts, offsets);
    scatter_kernel<<<(NNZ + 255) / 256, 256, 0, stream>>>(ker, row, col, vals,
                                                          offsets, cursor, meta, mval);
    stage1_kernel<<<NSEG, 384, 0, stream>>>(xp, offsets, counts, meta, mval, xk);
    stage2_kernel<<<(NPIX + 255) / 256, 256, 0, stream>>>(xk, W, bias, out);
}

// Round 2
// 426.430 us; speedup vs baseline: 1.1041x; 1.1041x over previous
//
#include <hip/hip_runtime.h>
#include <hip/hip_bf16.h>
#include <stdint.h>

typedef uint32_t u32;
typedef unsigned short u16;

#define NLAT_I 361
#define NLON_I 720
#define NLAT_O 181
#define NLON_O 360
#define KK 9
#define NNZ 120000
#define NSEG (KK * NLAT_O)            /* 1629 */
#define NPIX (NLAT_O * NLON_O)        /* 65160 */
#define NCH 32
#define NCP 16                        /* channel pairs */
#define XP_TOTAL (NLAT_I * 2 * NLON_O * NCP)  /* 4,158,720 u32 */
#define SORT_CAP 512

__device__ __forceinline__ u32 f2bf_rne(float f) {
    u32 b = __float_as_uint(f);
    return (b + 0x7FFFu + ((b >> 16) & 1u)) >> 16;
}

// ---------------- repack: x[32][361][720] f32 -> xp[hi][p][j][cp] bf16x2 ----
__global__ __launch_bounds__(256) void repack_kernel(const float* __restrict__ x,
                                                     u32* __restrict__ xp) {
    int tid = blockIdx.x * 256 + threadIdx.x;
    if (tid >= XP_TOTAL) return;
    int cp = tid & (NCP - 1);
    int j  = (tid >> 4) % NLON_O;
    int r  = tid / (NCP * NLON_O);    // r = hi*2 + p
    int p  = r & 1;
    int hi = r >> 1;
    int col = 2 * j + p;
    const int plane = NLAT_I * NLON_I;
    float f0 = x[(2 * cp) * plane + hi * NLON_I + col];
    float f1 = x[(2 * cp + 1) * plane + hi * NLON_I + col];
    xp[tid] = f2bf_rne(f0) | (f2bf_rne(f1) << 16);
}

// ---------------- CSR build ------------------------------------------------
__global__ __launch_bounds__(256) void hist_kernel(const int* __restrict__ ker,
                                                   const int* __restrict__ row,
                                                   int* __restrict__ counts) {
    int e = blockIdx.x * 256 + threadIdx.x;
    if (e >= NNZ) return;
    int seg = ker[e] * NLAT_O + row[e];
    atomicAdd(&counts[seg], 1);
}

__global__ __launch_bounds__(256) void scan_kernel(const int* __restrict__ counts,
                                                   int* __restrict__ offsets) {
    __shared__ int lsum[256];
    const int CH = 7;                  // 256*7 = 1792 >= 1629
    int t = threadIdx.x;
    int base = t * CH;
    int local[CH];
    int s = 0;
    for (int i = 0; i < CH; i++) {
        int v = (base + i < NSEG) ? counts[base + i] : 0;
        local[i] = s;
        s += v;
    }
    lsum[t] = s;
    __syncthreads();
    for (int off = 1; off < 256; off <<= 1) {
        int v = 0;
        if (t >= off) v = lsum[t - off];
        __syncthreads();
        if (t >= off) lsum[t] += v;
        __syncthreads();
    }
    int pre = (t == 0) ? 0 : lsum[t - 1];
    for (int i = 0; i < CH; i++) {
        if (base + i < NSEG) offsets[base + i] = pre + local[i];
    }
}

__global__ __launch_bounds__(256) void scatter_kernel(const int* __restrict__ ker,
                                                      const int* __restrict__ row,
                                                      const int* __restrict__ col,
                                                      const float* __restrict__ vals,
                                                      const int* __restrict__ offsets,
                                                      int* __restrict__ cursor,
                                                      int2* __restrict__ recs) {
    int e = blockIdx.x * 256 + threadIdx.x;
    if (e >= NNZ) return;
    int seg = ker[e] * NLAT_O + row[e];
    int pos = offsets[seg] + atomicAdd(&cursor[seg], 1);
    int c  = col[e];
    int hi = c / NLON_I;
    int wi = c % NLON_I;
    int p  = wi & 1;
    int a  = wi >> 1;                  // < 360
    u32 meta = ((u32)hi << 10) | ((u32)p << 9) | (u32)a;
    recs[pos] = make_int2((int)meta, __float_as_int(vals[e]));
}

// ---------------- per-segment sort by meta (hi,p,a ascending) --------------
// Sorting is a pure performance transform: it aligns the hi-sweep of all
// concurrently-running stage1 blocks, shrinking the live xp working set
// from 16.6 MB to a ~2 MB window that fits per-XCD L2.
__global__ __launch_bounds__(256) void sort_kernel(const int* __restrict__ offs,
                                                   const int* __restrict__ cnts,
                                                   int2* __restrict__ recs) {
    __shared__ u32 skey[SORT_CAP];
    __shared__ u32 sval[SORT_CAP];
    int s = blockIdx.x;
    int start = offs[s];
    int cnt = cnts[s];
    if (cnt > SORT_CAP) return;       // safety: leave unsorted (perf-only)
    int t = threadIdx.x;
    for (int i = t; i < cnt; i += 256) {
        int2 r = recs[start + i];
        skey[i] = (u32)r.x;
        sval[i] = (u32)r.y;
    }
    __syncthreads();
    for (int i = t; i < cnt; i += 256) {
        u32 k = skey[i];
        int rank = 0;
        for (int j = 0; j < cnt; j++) {
            u32 kj = skey[j];
            rank += (kj < k || (kj == k && j < i)) ? 1 : 0;
        }
        recs[start + rank] = make_int2((int)k, (int)sval[i]);
    }
}

// ---------------- stage1: per-segment gather-accumulate --------------------
#define UNP(u, c0, v)                                       \
    {                                                       \
        float lo_ = __uint_as_float((u) << 16);             \
        float hi_ = __uint_as_float((u) & 0xFFFF0000u);     \
        acc[c0] = fmaf(v, lo_, acc[c0]);                    \
        acc[c0 + 1] = fmaf(v, hi_, acc[c0 + 1]);            \
    }

#define UNP16(q0, q1, q2, q3, v)                            \
    UNP(q0.x, 0, v)  UNP(q0.y, 2, v)  UNP(q0.z, 4, v)  UNP(q0.w, 6, v)   \
    UNP(q1.x, 8, v)  UNP(q1.y, 10, v) UNP(q1.z, 12, v) UNP(q1.w, 14, v)  \
    UNP(q2.x, 16, v) UNP(q2.y, 18, v) UNP(q2.z, 20, v) UNP(q2.w, 22, v)  \
    UNP(q3.x, 24, v) UNP(q3.y, 26, v) UNP(q3.z, 28, v) UNP(q3.w, 30, v)

__global__ __launch_bounds__(384) void stage1_kernel(const u32* __restrict__ xp,
                                                     const int* __restrict__ offs,
                                                     const int* __restrict__ cnts,
                                                     const int2* __restrict__ recs,
                                                     u16* __restrict__ xk) {
    int s = blockIdx.x;
    int k = s / NLAT_O;
    int ho = s % NLAT_O;
    int wo = threadIdx.x;
    bool act = wo < NLON_O;
    int w = act ? wo : 0;

    float acc[NCH];
#pragma unroll
    for (int c = 0; c < NCH; c++) acc[c] = 0.0f;

    int start = offs[s];
    int cnt = cnts[s];

    int i = 0;
    for (; i + 2 <= cnt; i += 2) {
        int2 r0 = recs[start + i];
        int2 r1 = recs[start + i + 1];
        u32 m0 = (u32)r0.x;
        u32 m1 = (u32)r1.x;
        float v0 = __int_as_float(r0.y);
        float v1 = __int_as_float(r1.y);

        int row0 = (int)(m0 >> 9);          // hi*2+p
        int a0   = (int)(m0 & 0x1FF);
        int idx0 = a0 + w;
        idx0 = (idx0 >= NLON_O) ? idx0 - NLON_O : idx0;
        const uint4* rp0 = (const uint4*)(xp + ((size_t)(row0 * NLON_O + idx0) << 4));

        int row1 = (int)(m1 >> 9);
        int a1   = (int)(m1 & 0x1FF);
        int idx1 = a1 + w;
        idx1 = (idx1 >= NLON_O) ? idx1 - NLON_O : idx1;
        const uint4* rp1 = (const uint4*)(xp + ((size_t)(row1 * NLON_O + idx1) << 4));

        uint4 q0 = rp0[0];
        uint4 q1 = rp0[1];
        uint4 q2 = rp0[2];
        uint4 q3 = rp0[3];
        uint4 t0 = rp1[0];
        uint4 t1 = rp1[1];
        uint4 t2 = rp1[2];
        uint4 t3 = rp1[3];

        UNP16(q0, q1, q2, q3, v0)
        UNP16(t0, t1, t2, t3, v1)
    }
    if (i < cnt) {
        int2 r0 = recs[start + i];
        u32 m0 = (u32)r0.x;
        float v0 = __int_as_float(r0.y);
        int row0 = (int)(m0 >> 9);
        int a0   = (int)(m0 & 0x1FF);
        int idx0 = a0 + w;
        idx0 = (idx0 >= NLON_O) ? idx0 - NLON_O : idx0;
        const uint4* rp0 = (const uint4*)(xp + ((size_t)(row0 * NLON_O + idx0) << 4));
        uint4 q0 = rp0[0];
        uint4 q1 = rp0[1];
        uint4 q2 = rp0[2];
        uint4 q3 = rp0[3];
        UNP16(q0, q1, q2, q3, v0)
    }

    if (act) {
        int pix = ho * NLON_O + wo;
#pragma unroll
        for (int c = 0; c < NCH; c++) {
            xk[(size_t)(c * KK + k) * NPIX + pix] = (u16)f2bf_rne(acc[c]);
        }
    }
}

// ---------------- stage2: out[32][65160] = W[32][288] * xk[288][65160] -----
__global__ __launch_bounds__(256) void stage2_kernel(const u16* __restrict__ xk,
                                                     const float* __restrict__ W,
                                                     const float* __restrict__ bias,
                                                     float* __restrict__ out) {
    int pix = blockIdx.x * 256 + threadIdx.x;
    bool act = pix < NPIX;
    int px = act ? pix : 0;
    float acc[NCH];
#pragma unroll
    for (int o = 0; o < NCH; o++) acc[o] = 0.0f;
    for (int r = 0; r < NCH * KK; r++) {
        float xv = __uint_as_float(((u32)xk[(size_t)r * NPIX + px]) << 16);
#pragma unroll
        for (int o = 0; o < NCH; o++) {
            acc[o] = fmaf(W[o * (NCH * KK) + r], xv, acc[o]);
        }
    }
    if (act) {
#pragma unroll
        for (int o = 0; o < NCH; o++) {
            out[(size_t)o * NPIX + pix] = acc[o] + bias[o];
        }
    }
}

// ---------------- launch ---------------------------------------------------
extern "C" void kernel_launch(void* const* d_in, const int* in_sizes, int n_in,
                              void* d_out, int out_size, void* d_ws, size_t ws_size,
                              hipStream_t stream) {
    const float* x    = (const float*)d_in[0];
    const int* ker    = (const int*)d_in[1];
    const int* row    = (const int*)d_in[2];
    const int* col    = (const int*)d_in[3];
    const float* vals = (const float*)d_in[4];
    const float* W    = (const float*)d_in[5];
    const float* bias = (const float*)d_in[6];
    float* out        = (float*)d_out;

    char* ws = (char*)d_ws;
    const size_t off_xp   = 0;
    const size_t sz_xp    = (size_t)XP_TOTAL * 4;              // 16,634,880 (8-aligned)
    const size_t off_cnt  = off_xp + sz_xp;
    const size_t off_off  = off_cnt + 6528;
    const size_t off_cur  = off_off + 6528;
    const size_t off_rec  = off_cur + 6528;                    // 8-aligned
    const size_t off_xk   = off_rec + (size_t)NNZ * 8;

    u32* xp      = (u32*)(ws + off_xp);
    int* counts  = (int*)(ws + off_cnt);
    int* offsets = (int*)(ws + off_off);
    int* cursor  = (int*)(ws + off_cur);
    int2* recs   = (int2*)(ws + off_rec);
    u16* xk      = (u16*)(ws + off_xk);

    // zero counts + offsets + cursor
    hipMemsetAsync(ws + off_cnt, 0, 3 * 6528, stream);

    repack_kernel<<<(XP_TOTAL + 255) / 256, 256, 0, stream>>>(x, xp);
    hist_kernel<<<(NNZ + 255) / 256, 256, 0, stream>>>(ker, row, counts);
    scan_kernel<<<1, 256, 0, stream>>>(counts, offsets);
    scatter_kernel<<<(NNZ + 255) / 256, 256, 0, stream>>>(ker, row, col, vals,
                                                          offsets, cursor, recs);
    sort_kernel<<<NSEG, 256, 0, stream>>>(offsets, counts, recs);
    stage1_kernel<<<NSEG, 384, 0, stream>>>(xp, offsets, counts, recs, xk);
    stage2_kernel<<<(NPIX + 255) / 256, 256, 0, stream>>>(xk, W, bias, out);
}